// Round 4
// baseline (664.588 us; speedup 1.0000x reference)
//
#include <hip/hip_runtime.h>

// (B,S,D,K,F) = (4, 2048, 1024, 4, 4096)
static constexpr int Bb = 4;
static constexpr int Ss = 2048;
static constexpr int Dd = 1024;
static constexpr int Ff = 4096;
static constexpr int Mm = Bb * Ss;              // 8192 rows
static constexpr size_t ND = (size_t)Mm * Dd;   // 8388608
static constexpr int CH = 32;                   // scan chunks
static constexpr int CL = Ss / CH;              // chunk length 64

typedef __attribute__((ext_vector_type(8))) short short8;
typedef __attribute__((ext_vector_type(4))) float floatx4;

__device__ __forceinline__ unsigned f2bf(float f) {
  unsigned u = __builtin_bit_cast(unsigned, f);
  return (u + 0x7FFFu + ((u >> 16) & 1u)) >> 16;   // RNE
}
__device__ __forceinline__ float bf2f(unsigned bits) {
  return __builtin_bit_cast(float, bits << 16);
}
__device__ __forceinline__ void gload_lds16(const void* g, void* lds) {
  __builtin_amdgcn_global_load_lds((const __attribute__((address_space(1))) void*)g,
                                   (__attribute__((address_space(3))) void*)lds,
                                   16, 0, 0);
}

// ---------------- weight transpose + fp32->bf16: W[K][N] -> WT[N][K] --------
__global__ __launch_bounds__(256) void wconv_k(const float* __restrict__ W,
                                               unsigned short* __restrict__ WT,
                                               int K, int N) {
  __shared__ float tile[32][33];
  int tx = threadIdx.x & 31, ty = threadIdx.x >> 5;
  int bx = blockIdx.x * 32, by = blockIdx.y * 32;
#pragma unroll
  for (int i = 0; i < 32; i += 8)
    tile[ty + i][tx] = W[(size_t)(by + ty + i) * N + bx + tx];
  __syncthreads();
#pragma unroll
  for (int i = 0; i < 32; i += 8)
    WT[(size_t)(bx + ty + i) * K + by + tx] = (unsigned short)f2bf(tile[tx][ty + i]);
}

// ---------------- RMSNorm: fp32 in, bf16 out --------------------------------
__global__ __launch_bounds__(256) void rmsnorm_bf_k(const float* __restrict__ x,
                                                    const float* __restrict__ w,
                                                    unsigned short* __restrict__ out) {
  int row = blockIdx.x;
  const float4* xr = (const float4*)(x + (size_t)row * Dd);
  int t = threadIdx.x;
  float4 v = xr[t];
  float ss = v.x * v.x + v.y * v.y + v.z * v.z + v.w * v.w;
#pragma unroll
  for (int off = 32; off > 0; off >>= 1) ss += __shfl_down(ss, off, 64);
  __shared__ float sb[4];
  if ((t & 63) == 0) sb[t >> 6] = ss;
  __syncthreads();
  float tot = sb[0] + sb[1] + sb[2] + sb[3];
  float sc = rsqrtf(tot * (1.0f / (float)Dd) + 1e-6f);
  float4 wv = ((const float4*)w)[t];
  unsigned lo = f2bf(v.x * sc * wv.x) | (f2bf(v.y * sc * wv.y) << 16);
  unsigned hi = f2bf(v.z * sc * wv.z) | (f2bf(v.w * sc * wv.w) << 16);
  *(uint2*)(out + (size_t)row * Dd + t * 4) = make_uint2(lo, hi);
}

// ---------------- Causal depthwise conv (bf16 in/out) -> concat[:,0:D] ------
__global__ __launch_bounds__(256) void conv_k(const unsigned short* __restrict__ xn,
                                              const float* __restrict__ kern,
                                              const float* __restrict__ bias,
                                              unsigned short* __restrict__ outC) {
  size_t q = (size_t)blockIdx.x * 256 + threadIdx.x;  // over ND/4
  size_t i = q * 4;
  int d = (int)(i & (Dd - 1));
  int m = (int)(i >> 10);
  int t = m & (Ss - 1);
  float acc[4];
#pragma unroll
  for (int j = 0; j < 4; j++) acc[j] = bias[d + j];
#pragma unroll
  for (int k = 0; k < 4; k++) {
    if (t >= k) {
      uint2 xv = *(const uint2*)(xn + i - (size_t)k * Dd);
      float x0 = bf2f(xv.x & 0xFFFF), x1 = bf2f(xv.x >> 16);
      float x2 = bf2f(xv.y & 0xFFFF), x3 = bf2f(xv.y >> 16);
      acc[0] = fmaf(kern[(d + 0) * 4 + k], x0, acc[0]);
      acc[1] = fmaf(kern[(d + 1) * 4 + k], x1, acc[1]);
      acc[2] = fmaf(kern[(d + 2) * 4 + k], x2, acc[2]);
      acc[3] = fmaf(kern[(d + 3) * 4 + k], x3, acc[3]);
    }
  }
  unsigned lo = f2bf(acc[0]) | (f2bf(acc[1]) << 16);
  unsigned hi = f2bf(acc[2]) | (f2bf(acc[3]) << 16);
  *(uint2*)(outC + (size_t)m * (2 * Dd) + d) = make_uint2(lo, hi);
}

// ---------------- bf16 MFMA GEMM: C[M,N] = A[M,K] @ BT[N,K]^T ---------------
// 128x128 tile, BK=32, 4 waves 2x2, 4x4 16x16x32 MFMA subtiles/wave.
// XOR-swizzled LDS k-chunks (2-way-free bank access). MFMA operands swapped
// so each thread holds 4 consecutive N-cols of one M-row -> float4 epilogue.
// MODE bits: 1=+bias[col], 2=gelu, 4=+extra (fp32), 8=bf16 out, 16=velocity
template <int MODE>
__global__ __launch_bounds__(256) void bgemm_k(const unsigned short* __restrict__ A,
                                               const unsigned short* __restrict__ BT,
                                               void* __restrict__ Cout,
                                               int M, int N, int K,
                                               const float* __restrict__ bias,
                                               const float* __restrict__ extra,
                                               const float* __restrict__ vel_in,
                                               const float* __restrict__ x_in,
                                               const float* __restrict__ log_beta,
                                               float* __restrict__ vel_out) {
  __shared__ unsigned short As[128 * 32];
  __shared__ unsigned short Bs[128 * 32];
  const int tid = threadIdx.x;
  const int wave = tid >> 6, lane = tid & 63;
  const int r = lane & 15, quad = lane >> 4;
  const int wm = wave >> 1, wn = wave & 1;
  const int bm = blockIdx.y * 128, bn = blockIdx.x * 128;

  const unsigned short* Ab = A + (size_t)bm * K;
  const unsigned short* Bp = BT + (size_t)bn * K;
  const int srow = 32 * wave + (lane >> 2);                  // staging row
  const int scol = (((lane & 3) ^ ((lane >> 4) & 3))) * 8;   // swizzled k-chunk
  const int kcA = (quad ^ ((r >> 2) & 3)) * 8;               // read-side swizzle

  floatx4 acc[4][4];
#pragma unroll
  for (int i = 0; i < 4; i++)
#pragma unroll
    for (int j = 0; j < 4; j++) acc[i][j] = (floatx4){0.f, 0.f, 0.f, 0.f};

  for (int k0 = 0; k0 < K; k0 += 32) {
    __syncthreads();
    gload_lds16(Ab + (size_t)srow * K + k0 + scol,        As + wave * 1024);
    gload_lds16(Ab + (size_t)(srow + 16) * K + k0 + scol, As + wave * 1024 + 512);
    gload_lds16(Bp + (size_t)srow * K + k0 + scol,        Bs + wave * 1024);
    gload_lds16(Bp + (size_t)(srow + 16) * K + k0 + scol, Bs + wave * 1024 + 512);
    __syncthreads();
    short8 af[4], bfr[4];
#pragma unroll
    for (int i = 0; i < 4; i++)
      af[i] = *(const short8*)&As[(wm * 64 + i * 16 + r) * 32 + kcA];
#pragma unroll
    for (int j = 0; j < 4; j++)
      bfr[j] = *(const short8*)&Bs[(wn * 64 + j * 16 + r) * 32 + kcA];
#pragma unroll
    for (int i = 0; i < 4; i++)
#pragma unroll
      for (int j = 0; j < 4; j++)   // swapped operands: transposed C tile
        acc[i][j] = __builtin_amdgcn_mfma_f32_16x16x32_bf16(bfr[j], af[i], acc[i][j], 0, 0, 0);
  }

  // acc[i][j][0..3] = C[row = bm+wm*64+i*16+r][col = bn+wn*64+j*16+quad*4 +0..3]
#pragma unroll
  for (int i = 0; i < 4; i++) {
    int rowg = bm + wm * 64 + i * 16 + r;
#pragma unroll
    for (int j = 0; j < 4; j++) {
      int colg = bn + wn * 64 + j * 16 + quad * 4;
      size_t idx = (size_t)rowg * N + colg;
      float v0 = acc[i][j][0], v1 = acc[i][j][1], v2 = acc[i][j][2], v3 = acc[i][j][3];
      if (MODE & 1) {
        float4 bv = *(const float4*)(bias + colg);
        v0 += bv.x; v1 += bv.y; v2 += bv.z; v3 += bv.w;
      }
      if (MODE & 2) {
        float vv[4] = {v0, v1, v2, v3};
#pragma unroll
        for (int q2 = 0; q2 < 4; q2++) {
          float v = vv[q2];
          float c = v + 0.044715f * v * v * v;
          vv[q2] = 0.5f * v * (1.0f + tanhf(0.7978845608028654f * c));
        }
        v0 = vv[0]; v1 = vv[1]; v2 = vv[2]; v3 = vv[3];
      }
      if (MODE & 4) {
        float4 ev = *(const float4*)(extra + idx);
        v0 += ev.x; v1 += ev.y; v2 += ev.z; v3 += ev.w;
      }
      if (MODE & 16) {
        float4 lb = *(const float4*)(log_beta + colg);
        float4 vi = *(const float4*)(vel_in + idx);
        float4 xi = *(const float4*)(x_in + idx);
        float4 vn;
        vn.x = fmaf(1.0f / (1.0f + expf(-lb.x)), vi.x, v0);
        vn.y = fmaf(1.0f / (1.0f + expf(-lb.y)), vi.y, v1);
        vn.z = fmaf(1.0f / (1.0f + expf(-lb.z)), vi.z, v2);
        vn.w = fmaf(1.0f / (1.0f + expf(-lb.w)), vi.w, v3);
        *(float4*)(vel_out + idx) = vn;
        v0 = xi.x + vn.x; v1 = xi.y + vn.y; v2 = xi.z + vn.z; v3 = xi.w + vn.w;
      }
      if (MODE & 8) {
        uint2 pk;
        pk.x = f2bf(v0) | (f2bf(v1) << 16);
        pk.y = f2bf(v2) | (f2bf(v3) << 16);
        *(uint2*)((unsigned short*)Cout + idx) = pk;
      } else {
        float4 o; o.x = v0; o.y = v1; o.z = v2; o.w = v3;
        *(float4*)((float*)Cout + idx) = o;
      }
    }
  }
}

// ---------------- scan phase 1: gating + per-chunk (A, h_local) -------------
// gapre: [M, 2048] bf16 — cols 0..1023 = gate_pre, 1024..2047 = a_pre
__global__ __launch_bounds__(256) void scan_p1(const unsigned short* __restrict__ gapre,
                                               const unsigned short* __restrict__ xn,
                                               const float* __restrict__ lam,
                                               unsigned short* __restrict__ ub,
                                               float* __restrict__ carryA,
                                               float* __restrict__ carryH) {
  int g = blockIdx.x * 256 + threadIdx.x;    // 0..131071
  int e = g & (Dd - 1);
  int bc = g >> 10;
  int b = bc & 3;
  int c = bc >> 2;
  float l = lam[e];
  float sp = fmaxf(l, 0.0f) + log1pf(expf(-fabsf(l)));
  float m8sp = -8.0f * sp;
  size_t m0 = (size_t)b * Ss + (size_t)c * CL;
  float A = 1.0f, h = 0.0f;
#pragma unroll 4
  for (int t = 0; t < CL; t++) {
    size_t m = m0 + t;
    float gp = bf2f(gapre[m * 2048 + e]);
    float ap = bf2f(gapre[m * 2048 + 1024 + e]);
    float xv = bf2f(xn[m * Dd + e]);
    float sa = 1.0f / (1.0f + expf(-ap));
    float a = expf(m8sp * sa);
    float gg = 1.0f / (1.0f + expf(-gp));
    float u = sqrtf(fmaxf(1.0f - a * a, 0.0f)) * gg * xv;
    ub[m * Dd + e] = (unsigned short)f2bf(u);
    A *= a;
    h = fmaf(a, h, u);
  }
  carryA[c * 4096 + b * 1024 + e] = A;
  carryH[c * 4096 + b * 1024 + e] = h;
}

// ---------------- scan phase 2: scan carries -> per-chunk init state --------
__global__ __launch_bounds__(256) void scan_p2(const float* __restrict__ carryA,
                                               const float* __restrict__ carryH,
                                               float* __restrict__ init) {
  int ch = blockIdx.x * 256 + threadIdx.x;   // 0..4095
  float H = 0.0f;
#pragma unroll
  for (int c = 0; c < CH; c++) {
    init[c * 4096 + ch] = H;
    H = fmaf(carryA[c * 4096 + ch], H, carryH[c * 4096 + ch]);
  }
}

// ---------------- scan phase 3: rescan chunk with init -> concat[:,D:2D] ----
__global__ __launch_bounds__(256) void scan_p3(const unsigned short* __restrict__ gapre,
                                               const unsigned short* __restrict__ ub,
                                               const float* __restrict__ lam,
                                               const float* __restrict__ init,
                                               unsigned short* __restrict__ outC) {
  int g = blockIdx.x * 256 + threadIdx.x;
  int e = g & (Dd - 1);
  int bc = g >> 10;
  int b = bc & 3;
  int c = bc >> 2;
  float l = lam[e];
  float sp = fmaxf(l, 0.0f) + log1pf(expf(-fabsf(l)));
  float m8sp = -8.0f * sp;
  size_t m0 = (size_t)b * Ss + (size_t)c * CL;
  float h = init[c * 4096 + b * 1024 + e];
#pragma unroll 4
  for (int t = 0; t < CL; t++) {
    size_t m = m0 + t;
    float ap = bf2f(gapre[m * 2048 + 1024 + e]);
    float sa = 1.0f / (1.0f + expf(-ap));
    float a = expf(m8sp * sa);
    float u = bf2f(ub[m * Dd + e]);
    h = fmaf(a, h, u);
    outC[m * (2 * Dd) + Dd + e] = (unsigned short)f2bf(h);
  }
}

extern "C" void kernel_launch(void* const* d_in, const int* in_sizes, int n_in,
                              void* d_out, int out_size, void* d_ws, size_t ws_size,
                              hipStream_t stream) {
  const float* x        = (const float*)d_in[0];
  const float* velocity = (const float*)d_in[1];
  const float* pre_w    = (const float*)d_in[2];
  const float* conv_w   = (const float*)d_in[3];
  const float* conv_b   = (const float*)d_in[4];
  const float* W_gate   = (const float*)d_in[5];
  const float* W_a      = (const float*)d_in[6];
  const float* lam      = (const float*)d_in[7];
  const float* W_out    = (const float*)d_in[8];
  const float* b_out    = (const float*)d_in[9];
  const float* log_beta = (const float*)d_in[10];
  const float* ffn_w    = (const float*)d_in[11];
  const float* W_ff1    = (const float*)d_in[12];
  const float* b_ff1    = (const float*)d_in[13];
  const float* W_ff2    = (const float*)d_in[14];
  const float* b_ff2    = (const float*)d_in[15];

  float* out0 = (float*)d_out;
  float* out1 = out0 + ND;

  // ---- workspace (byte offsets), lifetime-aliased; peak 152 MB ----
  const size_t MB = 1024 * 1024;
  char* ws = (char*)d_ws;
  unsigned short* WgaT  = (unsigned short*)ws;               // 2048x1024 [0,4) (gate|a)
  unsigned short* WoT   = WgaT + (size_t)2 * 1024 * 1024;    // [4,8)
  unsigned short* Wf1T  = WoT + (size_t)2 * 1024 * 1024;     // [8,16)
  unsigned short* Wf2T  = Wf1T + (size_t)4 * 1024 * 1024;    // [16,24)
  float*          mixer = (float*)(ws + 24 * MB);            // 32 MB [24,56) — x_new
  float*          carA  = (float*)(ws + 24 * MB);            // overlay (pre-step-6)
  float*          carH  = (float*)(ws + 24 * MB + 512 * 1024);
  float*          initb = (float*)(ws + 25 * MB);
  unsigned short* conc  = (unsigned short*)(ws + 56 * MB);   // 32 MB [56,88)
  unsigned short* gapre = (unsigned short*)(ws + 88 * MB);   // 32 MB [88,120)
  unsigned short* xnbf  = (unsigned short*)(ws + 120 * MB);  // 16 MB [120,136)
  unsigned short* ubf   = (unsigned short*)(ws + 136 * MB);  // 16 MB [136,152)
  unsigned short* midbf = (unsigned short*)(ws + 88 * MB);   // 64 MB overlay [88,152)
  unsigned short* nrmbf = (unsigned short*)(ws + 56 * MB);   // overlay conc

  const int EB = 256;
  const int egrid4 = (int)(ND / 4 / EB);

  // 0. weight transpose + bf16 convert (WgT and WaT contiguous -> combined)
  wconv_k<<<dim3(32, 32),  256, 0, stream>>>(W_gate, WgaT, 1024, 1024);
  wconv_k<<<dim3(32, 32),  256, 0, stream>>>(W_a,    WgaT + (size_t)1024 * 1024, 1024, 1024);
  wconv_k<<<dim3(32, 64),  256, 0, stream>>>(W_out,  WoT, 2048, 1024);
  wconv_k<<<dim3(128, 32), 256, 0, stream>>>(W_ff1,  Wf1T, 1024, 4096);
  wconv_k<<<dim3(32, 128), 256, 0, stream>>>(W_ff2,  Wf2T, 4096, 1024);
  // 1. x_norm (bf16)
  rmsnorm_bf_k<<<Mm, 256, 0, stream>>>(x, pre_w, xnbf);
  // 2. conv -> concat[:, 0:D]
  conv_k<<<egrid4, EB, 0, stream>>>(xnbf, conv_w, conv_b, conc);
  // 3. fused gate_pre|a_pre GEMM (N=2048, bf16 out)
  bgemm_k<8><<<dim3(16, 64), 256, 0, stream>>>(xnbf, WgaT, gapre, Mm, 2048, 1024,
      nullptr, nullptr, nullptr, nullptr, nullptr, nullptr);
  // 4-5. chunked scan (gating fused into P1) -> concat[:, D:2D]
  scan_p1<<<512, 256, 0, stream>>>(gapre, xnbf, lam, ubf, carA, carH);
  scan_p2<<<16, 256, 0, stream>>>(carA, carH, initb);
  scan_p3<<<512, 256, 0, stream>>>(gapre, ubf, lam, initb, conc);
  // 6. mixer GEMM + fused velocity/x_new epilogue: mixer=x_new, out1=velocity
  bgemm_k<1 | 16><<<dim3(8, 64), 256, 0, stream>>>(conc, WoT, mixer, Mm, 1024, 2048,
      b_out, nullptr, velocity, x, log_beta, out1);
  // 8. normed = rmsnorm(x_new) (bf16)
  rmsnorm_bf_k<<<Mm, 256, 0, stream>>>(mixer, ffn_w, nrmbf);
  // 9. mid = gelu(normed @ W_ff1 + b_ff1) (bf16)
  bgemm_k<1 | 2 | 8><<<dim3(32, 64), 256, 0, stream>>>(nrmbf, Wf1T, midbf, Mm, 4096, 1024,
      b_ff1, nullptr, nullptr, nullptr, nullptr, nullptr);
  // 10. out0 = mid @ W_ff2 + b_ff2 + x_new (fp32)
  bgemm_k<1 | 4><<<dim3(8, 64), 256, 0, stream>>>(midbf, Wf2T, out0, Mm, 1024, 4096,
      b_ff2, mixer, nullptr, nullptr, nullptr, nullptr);
}

// Round 5
// 646.021 us; speedup vs baseline: 1.0287x; 1.0287x over previous
//
#include <hip/hip_runtime.h>

// (B,S,D,K,F) = (4, 2048, 1024, 4, 4096)
static constexpr int Bb = 4;
static constexpr int Ss = 2048;
static constexpr int Dd = 1024;
static constexpr int Ff = 4096;
static constexpr int Mm = Bb * Ss;              // 8192 rows
static constexpr size_t ND = (size_t)Mm * Dd;   // 8388608
static constexpr int CH = 32;                   // scan chunks
static constexpr int CL = Ss / CH;              // chunk length 64

typedef __attribute__((ext_vector_type(8))) short short8;
typedef __attribute__((ext_vector_type(4))) float floatx4;

__device__ __forceinline__ unsigned f2bf(float f) {
  unsigned u = __builtin_bit_cast(unsigned, f);
  return (u + 0x7FFFu + ((u >> 16) & 1u)) >> 16;   // RNE
}
__device__ __forceinline__ float bf2f(unsigned bits) {
  return __builtin_bit_cast(float, bits << 16);
}
__device__ __forceinline__ void gload_lds16(const void* g, void* lds) {
  __builtin_amdgcn_global_load_lds((const __attribute__((address_space(1))) void*)g,
                                   (__attribute__((address_space(3))) void*)lds,
                                   16, 0, 0);
}
// fast sigmoid / tanh-gelu via hw v_exp_f32 + v_rcp_f32 (f32-accurate ~1e-6)
__device__ __forceinline__ float fsig(float x) {
  return __builtin_amdgcn_rcpf(1.0f + __expf(-x));
}
__device__ __forceinline__ float fgelu(float v) {
  // 0.5v(1+tanh(0.79788456(v+0.044715v^3))) == v * sigmoid(1.59576912(v+0.044715v^3))
  float z = 1.5957691216057308f * fmaf(0.044715f * v, v * v, v);
  return v * __builtin_amdgcn_rcpf(1.0f + __expf(-z));
}

// ---------------- weight transpose + fp32->bf16: W[K][N] -> WT[N][K] --------
__global__ __launch_bounds__(256) void wconv_k(const float* __restrict__ W,
                                               unsigned short* __restrict__ WT,
                                               int K, int N) {
  __shared__ float tile[32][33];
  int tx = threadIdx.x & 31, ty = threadIdx.x >> 5;
  int bx = blockIdx.x * 32, by = blockIdx.y * 32;
#pragma unroll
  for (int i = 0; i < 32; i += 8)
    tile[ty + i][tx] = W[(size_t)(by + ty + i) * N + bx + tx];
  __syncthreads();
#pragma unroll
  for (int i = 0; i < 32; i += 8)
    WT[(size_t)(bx + ty + i) * K + by + tx] = (unsigned short)f2bf(tile[tx][ty + i]);
}

// ---------------- RMSNorm: fp32 in, bf16 out --------------------------------
__global__ __launch_bounds__(256) void rmsnorm_bf_k(const float* __restrict__ x,
                                                    const float* __restrict__ w,
                                                    unsigned short* __restrict__ out) {
  int row = blockIdx.x;
  const float4* xr = (const float4*)(x + (size_t)row * Dd);
  int t = threadIdx.x;
  float4 v = xr[t];
  float ss = v.x * v.x + v.y * v.y + v.z * v.z + v.w * v.w;
#pragma unroll
  for (int off = 32; off > 0; off >>= 1) ss += __shfl_down(ss, off, 64);
  __shared__ float sb[4];
  if ((t & 63) == 0) sb[t >> 6] = ss;
  __syncthreads();
  float tot = sb[0] + sb[1] + sb[2] + sb[3];
  float sc = rsqrtf(tot * (1.0f / (float)Dd) + 1e-6f);
  float4 wv = ((const float4*)w)[t];
  unsigned lo = f2bf(v.x * sc * wv.x) | (f2bf(v.y * sc * wv.y) << 16);
  unsigned hi = f2bf(v.z * sc * wv.z) | (f2bf(v.w * sc * wv.w) << 16);
  *(uint2*)(out + (size_t)row * Dd + t * 4) = make_uint2(lo, hi);
}

// ---------------- Causal depthwise conv (bf16 in/out) -> concat[:,0:D] ------
__global__ __launch_bounds__(256) void conv_k(const unsigned short* __restrict__ xn,
                                              const float* __restrict__ kern,
                                              const float* __restrict__ bias,
                                              unsigned short* __restrict__ outC) {
  size_t q = (size_t)blockIdx.x * 256 + threadIdx.x;  // over ND/4
  size_t i = q * 4;
  int d = (int)(i & (Dd - 1));
  int m = (int)(i >> 10);
  int t = m & (Ss - 1);
  float acc[4];
#pragma unroll
  for (int j = 0; j < 4; j++) acc[j] = bias[d + j];
#pragma unroll
  for (int k = 0; k < 4; k++) {
    if (t >= k) {
      uint2 xv = *(const uint2*)(xn + i - (size_t)k * Dd);
      float x0 = bf2f(xv.x & 0xFFFF), x1 = bf2f(xv.x >> 16);
      float x2 = bf2f(xv.y & 0xFFFF), x3 = bf2f(xv.y >> 16);
      acc[0] = fmaf(kern[(d + 0) * 4 + k], x0, acc[0]);
      acc[1] = fmaf(kern[(d + 1) * 4 + k], x1, acc[1]);
      acc[2] = fmaf(kern[(d + 2) * 4 + k], x2, acc[2]);
      acc[3] = fmaf(kern[(d + 3) * 4 + k], x3, acc[3]);
    }
  }
  unsigned lo = f2bf(acc[0]) | (f2bf(acc[1]) << 16);
  unsigned hi = f2bf(acc[2]) | (f2bf(acc[3]) << 16);
  *(uint2*)(outC + (size_t)m * (2 * Dd) + d) = make_uint2(lo, hi);
}

// ---------------- bf16 MFMA GEMM: C[M,N] = A[M,K] @ BT[N,K]^T ---------------
// 128x128 tile, BK=32, 4 waves 2x2, 4x4 16x16x32 MFMA subtiles/wave.
// Contiguous lane-ordered LDS stage/read (m97 pattern — round-4 swizzle
// regressed 30%, reverted). Swapped MFMA operands: thread holds
// C[row=..+r][col=..+quad*4+reg] -> float4/uint2 vectorized epilogue.
// MODE bits: 1=+bias[col], 2=gelu, 4=+extra (fp32), 8=bf16 out, 16=velocity
template <int MODE>
__global__ __launch_bounds__(256) void bgemm_k(const unsigned short* __restrict__ A,
                                               const unsigned short* __restrict__ BT,
                                               void* __restrict__ Cout,
                                               int M, int N, int K,
                                               const float* __restrict__ bias,
                                               const float* __restrict__ extra,
                                               const float* __restrict__ vel_in,
                                               const float* __restrict__ x_in,
                                               const float* __restrict__ log_beta,
                                               float* __restrict__ vel_out) {
  __shared__ unsigned short As[128 * 32];
  __shared__ unsigned short Bs[128 * 32];
  const int tid = threadIdx.x;
  const int wave = tid >> 6, lane = tid & 63;
  const int r = lane & 15, quad = lane >> 4;
  const int wm = wave >> 1, wn = wave & 1;
  const int bm = blockIdx.y * 128, bn = blockIdx.x * 128;

  const unsigned short* Ab = A + (size_t)bm * K;
  const unsigned short* Bp = BT + (size_t)bn * K;
  const int srow = 32 * wave + (lane >> 2);   // staging row
  const int scol = (lane & 3) * 8;            // staging k-offset (contiguous)

  floatx4 acc[4][4];
#pragma unroll
  for (int i = 0; i < 4; i++)
#pragma unroll
    for (int j = 0; j < 4; j++) acc[i][j] = (floatx4){0.f, 0.f, 0.f, 0.f};

  for (int k0 = 0; k0 < K; k0 += 32) {
    __syncthreads();
    gload_lds16(Ab + (size_t)srow * K + k0 + scol,        As + wave * 1024);
    gload_lds16(Ab + (size_t)(srow + 16) * K + k0 + scol, As + wave * 1024 + 512);
    gload_lds16(Bp + (size_t)srow * K + k0 + scol,        Bs + wave * 1024);
    gload_lds16(Bp + (size_t)(srow + 16) * K + k0 + scol, Bs + wave * 1024 + 512);
    __syncthreads();
    short8 af[4], bfr[4];
#pragma unroll
    for (int i = 0; i < 4; i++)
      af[i] = *(const short8*)&As[(wm * 64 + i * 16 + r) * 32 + quad * 8];
#pragma unroll
    for (int j = 0; j < 4; j++)
      bfr[j] = *(const short8*)&Bs[(wn * 64 + j * 16 + r) * 32 + quad * 8];
#pragma unroll
    for (int i = 0; i < 4; i++)
#pragma unroll
      for (int j = 0; j < 4; j++)   // swapped operands: transposed C fragment
        acc[i][j] = __builtin_amdgcn_mfma_f32_16x16x32_bf16(bfr[j], af[i], acc[i][j], 0, 0, 0);
  }

  // acc[i][j][0..3] = C[row = bm+wm*64+i*16+r][col = bn+wn*64+j*16+quad*4 +0..3]
#pragma unroll
  for (int i = 0; i < 4; i++) {
    int rowg = bm + wm * 64 + i * 16 + r;
#pragma unroll
    for (int j = 0; j < 4; j++) {
      int colg = bn + wn * 64 + j * 16 + quad * 4;
      size_t idx = (size_t)rowg * N + colg;
      float v0 = acc[i][j][0], v1 = acc[i][j][1], v2 = acc[i][j][2], v3 = acc[i][j][3];
      if (MODE & 1) {
        float4 bv = *(const float4*)(bias + colg);
        v0 += bv.x; v1 += bv.y; v2 += bv.z; v3 += bv.w;
      }
      if (MODE & 2) {
        v0 = fgelu(v0); v1 = fgelu(v1); v2 = fgelu(v2); v3 = fgelu(v3);
      }
      if (MODE & 4) {
        float4 ev = *(const float4*)(extra + idx);
        v0 += ev.x; v1 += ev.y; v2 += ev.z; v3 += ev.w;
      }
      if (MODE & 16) {
        float4 lb = *(const float4*)(log_beta + colg);
        float4 vi = *(const float4*)(vel_in + idx);
        float4 xi = *(const float4*)(x_in + idx);
        float4 vn;
        vn.x = fmaf(fsig(lb.x), vi.x, v0);
        vn.y = fmaf(fsig(lb.y), vi.y, v1);
        vn.z = fmaf(fsig(lb.z), vi.z, v2);
        vn.w = fmaf(fsig(lb.w), vi.w, v3);
        *(float4*)(vel_out + idx) = vn;
        v0 = xi.x + vn.x; v1 = xi.y + vn.y; v2 = xi.z + vn.z; v3 = xi.w + vn.w;
      }
      if (MODE & 8) {
        uint2 pk;
        pk.x = f2bf(v0) | (f2bf(v1) << 16);
        pk.y = f2bf(v2) | (f2bf(v3) << 16);
        *(uint2*)((unsigned short*)Cout + idx) = pk;
      } else {
        float4 o; o.x = v0; o.y = v1; o.z = v2; o.w = v3;
        *(float4*)((float*)Cout + idx) = o;
      }
    }
  }
}

// ---------------- scan phase 1: gating + per-chunk (A, h_local) -------------
// gapre: [M, 2048] bf16 — cols 0..1023 = gate_pre, 1024..2047 = a_pre
__global__ __launch_bounds__(256) void scan_p1(const unsigned short* __restrict__ gapre,
                                               const unsigned short* __restrict__ xn,
                                               const float* __restrict__ lam,
                                               unsigned short* __restrict__ ub,
                                               float* __restrict__ carryA,
                                               float* __restrict__ carryH) {
  int g = blockIdx.x * 256 + threadIdx.x;    // 0..131071
  int e = g & (Dd - 1);
  int bc = g >> 10;
  int b = bc & 3;
  int c = bc >> 2;
  float l = lam[e];
  float sp = fmaxf(l, 0.0f) + log1pf(__expf(-fabsf(l)));
  float m8sp = -8.0f * sp;
  size_t m0 = (size_t)b * Ss + (size_t)c * CL;
  float A = 1.0f, h = 0.0f;
#pragma unroll 4
  for (int t = 0; t < CL; t++) {
    size_t m = m0 + t;
    float gp = bf2f(gapre[m * 2048 + e]);
    float ap = bf2f(gapre[m * 2048 + 1024 + e]);
    float xv = bf2f(xn[m * Dd + e]);
    float a = __expf(m8sp * fsig(ap));
    float u = sqrtf(fmaxf(1.0f - a * a, 0.0f)) * fsig(gp) * xv;
    ub[m * Dd + e] = (unsigned short)f2bf(u);
    A *= a;
    h = fmaf(a, h, u);
  }
  carryA[c * 4096 + b * 1024 + e] = A;
  carryH[c * 4096 + b * 1024 + e] = h;
}

// ---------------- scan phase 2: scan carries -> per-chunk init state --------
__global__ __launch_bounds__(256) void scan_p2(const float* __restrict__ carryA,
                                               const float* __restrict__ carryH,
                                               float* __restrict__ init) {
  int ch = blockIdx.x * 256 + threadIdx.x;   // 0..4095
  float H = 0.0f;
#pragma unroll
  for (int c = 0; c < CH; c++) {
    init[c * 4096 + ch] = H;
    H = fmaf(carryA[c * 4096 + ch], H, carryH[c * 4096 + ch]);
  }
}

// ---------------- scan phase 3: rescan chunk with init -> concat[:,D:2D] ----
__global__ __launch_bounds__(256) void scan_p3(const unsigned short* __restrict__ gapre,
                                               const unsigned short* __restrict__ ub,
                                               const float* __restrict__ lam,
                                               const float* __restrict__ init,
                                               unsigned short* __restrict__ outC) {
  int g = blockIdx.x * 256 + threadIdx.x;
  int e = g & (Dd - 1);
  int bc = g >> 10;
  int b = bc & 3;
  int c = bc >> 2;
  float l = lam[e];
  float sp = fmaxf(l, 0.0f) + log1pf(__expf(-fabsf(l)));
  float m8sp = -8.0f * sp;
  size_t m0 = (size_t)b * Ss + (size_t)c * CL;
  float h = init[c * 4096 + b * 1024 + e];
#pragma unroll 4
  for (int t = 0; t < CL; t++) {
    size_t m = m0 + t;
    float ap = bf2f(gapre[m * 2048 + 1024 + e]);
    float a = __expf(m8sp * fsig(ap));
    float u = bf2f(ub[m * Dd + e]);
    h = fmaf(a, h, u);
    outC[m * (2 * Dd) + Dd + e] = (unsigned short)f2bf(h);
  }
}

extern "C" void kernel_launch(void* const* d_in, const int* in_sizes, int n_in,
                              void* d_out, int out_size, void* d_ws, size_t ws_size,
                              hipStream_t stream) {
  const float* x        = (const float*)d_in[0];
  const float* velocity = (const float*)d_in[1];
  const float* pre_w    = (const float*)d_in[2];
  const float* conv_w   = (const float*)d_in[3];
  const float* conv_b   = (const float*)d_in[4];
  const float* W_gate   = (const float*)d_in[5];
  const float* W_a      = (const float*)d_in[6];
  const float* lam      = (const float*)d_in[7];
  const float* W_out    = (const float*)d_in[8];
  const float* b_out    = (const float*)d_in[9];
  const float* log_beta = (const float*)d_in[10];
  const float* ffn_w    = (const float*)d_in[11];
  const float* W_ff1    = (const float*)d_in[12];
  const float* b_ff1    = (const float*)d_in[13];
  const float* W_ff2    = (const float*)d_in[14];
  const float* b_ff2    = (const float*)d_in[15];

  float* out0 = (float*)d_out;
  float* out1 = out0 + ND;

  // ---- workspace (byte offsets), lifetime-aliased; peak 152 MB ----
  const size_t MB = 1024 * 1024;
  char* ws = (char*)d_ws;
  unsigned short* WgaT  = (unsigned short*)ws;               // 2048x1024 [0,4) (gate|a)
  unsigned short* WoT   = WgaT + (size_t)2 * 1024 * 1024;    // [4,8)
  unsigned short* Wf1T  = WoT + (size_t)2 * 1024 * 1024;     // [8,16)
  unsigned short* Wf2T  = Wf1T + (size_t)4 * 1024 * 1024;    // [16,24)
  float*          mixer = (float*)(ws + 24 * MB);            // 32 MB [24,56) — x_new
  float*          carA  = (float*)(ws + 24 * MB);            // overlay (pre-step-6)
  float*          carH  = (float*)(ws + 24 * MB + 512 * 1024);
  float*          initb = (float*)(ws + 25 * MB);
  unsigned short* conc  = (unsigned short*)(ws + 56 * MB);   // 32 MB [56,88)
  unsigned short* gapre = (unsigned short*)(ws + 88 * MB);   // 32 MB [88,120)
  unsigned short* xnbf  = (unsigned short*)(ws + 120 * MB);  // 16 MB [120,136)
  unsigned short* ubf   = (unsigned short*)(ws + 136 * MB);  // 16 MB [136,152)
  unsigned short* midbf = (unsigned short*)(ws + 88 * MB);   // 64 MB overlay [88,152)
  unsigned short* nrmbf = (unsigned short*)(ws + 56 * MB);   // overlay conc

  const int EB = 256;
  const int egrid4 = (int)(ND / 4 / EB);

  // 0. weight transpose + bf16 convert (gate|a combined, contiguous)
  wconv_k<<<dim3(32, 32),  256, 0, stream>>>(W_gate, WgaT, 1024, 1024);
  wconv_k<<<dim3(32, 32),  256, 0, stream>>>(W_a,    WgaT + (size_t)1024 * 1024, 1024, 1024);
  wconv_k<<<dim3(32, 64),  256, 0, stream>>>(W_out,  WoT, 2048, 1024);
  wconv_k<<<dim3(128, 32), 256, 0, stream>>>(W_ff1,  Wf1T, 1024, 4096);
  wconv_k<<<dim3(32, 128), 256, 0, stream>>>(W_ff2,  Wf2T, 4096, 1024);
  // 1. x_norm (bf16)
  rmsnorm_bf_k<<<Mm, 256, 0, stream>>>(x, pre_w, xnbf);
  // 2. conv -> concat[:, 0:D]
  conv_k<<<egrid4, EB, 0, stream>>>(xnbf, conv_w, conv_b, conc);
  // 3. fused gate_pre|a_pre GEMM (N=2048, bf16 out)
  bgemm_k<8><<<dim3(16, 64), 256, 0, stream>>>(xnbf, WgaT, gapre, Mm, 2048, 1024,
      nullptr, nullptr, nullptr, nullptr, nullptr, nullptr);
  // 4-5. chunked scan (gating fused into P1) -> concat[:, D:2D]
  scan_p1<<<512, 256, 0, stream>>>(gapre, xnbf, lam, ubf, carA, carH);
  scan_p2<<<16, 256, 0, stream>>>(carA, carH, initb);
  scan_p3<<<512, 256, 0, stream>>>(gapre, ubf, lam, initb, conc);
  // 6. mixer GEMM + fused velocity/x_new epilogue: mixer=x_new, out1=velocity
  bgemm_k<1 | 16><<<dim3(8, 64), 256, 0, stream>>>(conc, WoT, mixer, Mm, 1024, 2048,
      b_out, nullptr, velocity, x, log_beta, out1);
  // 8. normed = rmsnorm(x_new) (bf16)
  rmsnorm_bf_k<<<Mm, 256, 0, stream>>>(mixer, ffn_w, nrmbf);
  // 9. mid = gelu(normed @ W_ff1 + b_ff1) (bf16)
  bgemm_k<1 | 2 | 8><<<dim3(32, 64), 256, 0, stream>>>(nrmbf, Wf1T, midbf, Mm, 4096, 1024,
      b_ff1, nullptr, nullptr, nullptr, nullptr, nullptr);
  // 10. out0 = mid @ W_ff2 + b_ff2 + x_new (fp32)
  bgemm_k<1 | 4><<<dim3(8, 64), 256, 0, stream>>>(midbf, Wf2T, out0, Mm, 1024, 4096,
      b_ff2, mixer, nullptr, nullptr, nullptr, nullptr);
}